// Round 4
// baseline (23584.500 us; speedup 1.0000x reference)
//
#include <hip/hip_runtime.h>
#include <math.h>

#define Bsz 16
#define Tsz 1000
#define Nsz 100
#define ENC 512
#define VOCAB 10025
#define EMB 640
#define HID 1024
#define ATT 1024
#define KX (EMB + ENC)          // 1152
#define KRO (HID + EMB + ENC)   // 2176
#define G4 (4 * HID)            // 4096

typedef short s16x8 __attribute__((ext_vector_type(8)));
typedef unsigned short u16x4 __attribute__((ext_vector_type(4)));
typedef unsigned short u16x8 __attribute__((ext_vector_type(8)));
typedef float f32x4 __attribute__((ext_vector_type(4)));

__device__ __forceinline__ float4 ld4(const float* p) { return *reinterpret_cast<const float4*>(p); }
__device__ __forceinline__ float dot4(float4 a, float4 b) { return a.x*b.x + a.y*b.y + a.z*b.z + a.w*b.w; }
__device__ __forceinline__ float sigmoidf_(float x) { return 1.f / (1.f + __expf(-x)); }
__device__ __forceinline__ float ftanh_(float x) {
    float e = __expf(2.f * x);
    return 1.f - 2.f / (e + 1.f);   // exp overflow -> 1, underflow -> -1 (no clamp needed)
}
__device__ __forceinline__ unsigned short f2bf(float x) {
    union { float f; unsigned u; } v; v.f = x;
    unsigned r = v.u + 0x7fffu + ((v.u >> 16) & 1u);
    return (unsigned short)(r >> 16);
}
__device__ __forceinline__ float bf2f(unsigned short h) {
    union { float f; unsigned u; } v; v.u = ((unsigned)h) << 16;
    return v.f;
}

// device-wide barrier: monotone counter, agent scope. All 256 blocks co-resident
// (1 block/CU enforced by 115 KB LDS). __threadfence gives agent-scope release of
// each thread's writes; acquire load invalidates L1/L2 on the waiting side.
__device__ __forceinline__ void gsync(unsigned* ctr, unsigned target) {
    __threadfence();
    __syncthreads();
    if (threadIdx.x == 0) {
        __hip_atomic_fetch_add(ctr, 1u, __ATOMIC_ACQ_REL, __HIP_MEMORY_SCOPE_AGENT);
        while (__hip_atomic_load(ctr, __ATOMIC_ACQUIRE, __HIP_MEMORY_SCOPE_AGENT) < target)
            __builtin_amdgcn_s_sleep(2);
    }
    __syncthreads();
}

// ---------------- init: zero accum + bias sum + barrier ----------------
__global__ __launch_bounds__(256) void k_init(float* accum, const float* __restrict__ bih,
                                              const float* __restrict__ bhh, float* __restrict__ bsum,
                                              unsigned* bar) {
    int i = blockIdx.x * 256 + threadIdx.x;
    if (i < Bsz * Tsz) accum[i] = 0.f;
    if (i < G4) bsum[i] = bih[i] + bhh[i];
    if (i == 0) *bar = 0u;
}

// ---------------- shifted embedding into roA[:, HID:HID+EMB] ----------------
__global__ __launch_bounds__(256) void k_embed(const int* __restrict__ labels,
                                               const float* __restrict__ table,
                                               float* __restrict__ roA) {
    int idx = blockIdx.x * 256 + threadIdx.x;
    if (idx >= Bsz * Nsz * EMB) return;
    int e = idx % EMB;
    int bn = idx / EMB;
    int n = bn % Nsz, b = bn / Nsz;
    float v = 0.f;
    if (n > 0) {
        int lab = labels[b * Nsz + n - 1];
        v = table[(size_t)lab * EMB + e];
    }
    roA[(size_t)bn * KRO + HID + e] = v;
}

// ======== MFMA split-bf16 GEMM: C = A[M,K](lda) @ W[Nc,K](ldw)^T + bias ========
// MODE 0: fp32 out. MODE 1: maxout pairs fp32 out. MODE 2: bf16 out.
template <int MODE>
__global__ __launch_bounds__(256) void mfma_gemm(const float* __restrict__ A, int lda,
                                                 const float* __restrict__ W, int ldw,
                                                 const float* __restrict__ bias,
                                                 float* __restrict__ C,
                                                 int M, int Nc, int K, int ldC) {
    __shared__ unsigned short Ah[128][40], Al[128][40], Wh[128][40], Wl[128][40];
    int tid = threadIdx.x;
    int lane = tid & 63;
    int wave = tid >> 6;
    int wm = (wave >> 1) * 64, wn = (wave & 1) * 64;
    int m0 = blockIdx.y * 128, n0 = blockIdx.x * 128;
    int lrow = tid >> 1;
    int lcol = (tid & 1) * 16;
    bool aval = (m0 + lrow) < M;
    bool wval = (n0 + lrow) < Nc;
    const float* Arow = A + (size_t)(m0 + lrow) * lda + lcol;
    const float* Wrow = W + (size_t)(n0 + lrow) * ldw + lcol;
    int frow = lane & 15, fk = (lane >> 4) * 8;

    f32x4 acc[4][4];
#pragma unroll
    for (int i = 0; i < 4; i++)
#pragma unroll
        for (int j = 0; j < 4; j++) acc[i][j] = (f32x4){0.f, 0.f, 0.f, 0.f};

    const float4 z4 = {0.f, 0.f, 0.f, 0.f};
    for (int k0 = 0; k0 < K; k0 += 32) {
#pragma unroll
        for (int c = 0; c < 16; c += 4) {
            float4 av = aval ? ld4(Arow + k0 + c) : z4;
            u16x4 hv, lv;
            hv.x = f2bf(av.x); lv.x = f2bf(av.x - bf2f(hv.x));
            hv.y = f2bf(av.y); lv.y = f2bf(av.y - bf2f(hv.y));
            hv.z = f2bf(av.z); lv.z = f2bf(av.z - bf2f(hv.z));
            hv.w = f2bf(av.w); lv.w = f2bf(av.w - bf2f(hv.w));
            *(u16x4*)&Ah[lrow][lcol + c] = hv;
            *(u16x4*)&Al[lrow][lcol + c] = lv;
            float4 wv = wval ? ld4(Wrow + k0 + c) : z4;
            hv.x = f2bf(wv.x); lv.x = f2bf(wv.x - bf2f(hv.x));
            hv.y = f2bf(wv.y); lv.y = f2bf(wv.y - bf2f(hv.y));
            hv.z = f2bf(wv.z); lv.z = f2bf(wv.z - bf2f(hv.z));
            hv.w = f2bf(wv.w); lv.w = f2bf(wv.w - bf2f(hv.w));
            *(u16x4*)&Wh[lrow][lcol + c] = hv;
            *(u16x4*)&Wl[lrow][lcol + c] = lv;
        }
        __syncthreads();
        s16x8 afh[4], afl[4], bfh[4], bfl[4];
#pragma unroll
        for (int i = 0; i < 4; i++) {
            afh[i] = *(const s16x8*)&Ah[wm + i * 16 + frow][fk];
            afl[i] = *(const s16x8*)&Al[wm + i * 16 + frow][fk];
            bfh[i] = *(const s16x8*)&Wh[wn + i * 16 + frow][fk];
            bfl[i] = *(const s16x8*)&Wl[wn + i * 16 + frow][fk];
        }
#pragma unroll
        for (int mi = 0; mi < 4; mi++)
#pragma unroll
            for (int ni = 0; ni < 4; ni++) {
                acc[mi][ni] = __builtin_amdgcn_mfma_f32_16x16x32_bf16(afh[mi], bfh[ni], acc[mi][ni], 0, 0, 0);
                acc[mi][ni] = __builtin_amdgcn_mfma_f32_16x16x32_bf16(afl[mi], bfh[ni], acc[mi][ni], 0, 0, 0);
                acc[mi][ni] = __builtin_amdgcn_mfma_f32_16x16x32_bf16(afh[mi], bfl[ni], acc[mi][ni], 0, 0, 0);
            }
        __syncthreads();
    }
    int crb = (lane >> 4) * 4;
    int ccol = lane & 15;
#pragma unroll
    for (int mi = 0; mi < 4; mi++) {
#pragma unroll
        for (int r = 0; r < 4; r++) {
            int m = m0 + wm + mi * 16 + crb + r;
#pragma unroll
            for (int ni = 0; ni < 4; ni++) {
                int n = n0 + wn + ni * 16 + ccol;
                if (MODE == 0) {
                    if (m < M && n < Nc) C[(size_t)m * ldC + n] = acc[mi][ni][r] + bias[n];
                } else if (MODE == 2) {
                    if (m < M && n < Nc)
                        ((unsigned short*)C)[(size_t)m * ldC + n] = f2bf(acc[mi][ni][r] + bias[n]);
                } else {
                    float v = (n < Nc) ? acc[mi][ni][r] + bias[n] : -INFINITY;
                    float o = __shfl_xor(v, 1, 64);
                    if (((lane & 1) == 0) && m < M && n < Nc)
                        C[(size_t)m * ldC + (n >> 1)] = fmaxf(v, o);
                }
            }
        }
    }
}

// ---------------- inv_fertility ----------------
__global__ __launch_bounds__(256) void k_ifert(const float* __restrict__ enc,
                                               const float* __restrict__ Wfert,
                                               float* __restrict__ ifert) {
    int wv = (blockIdx.x * 256 + threadIdx.x) >> 6;
    int lane = threadIdx.x & 63;
    if (wv >= Bsz * Tsz) return;
    const float* row = enc + (size_t)wv * ENC;
    float s = 0.f;
    for (int k = lane * 4; k < ENC; k += 256) s += dot4(ld4(row + k), ld4(Wfert + k));
    for (int o = 32; o; o >>= 1) s += __shfl_xor(s, o, 64);
    if (lane == 0) ifert[wv] = 1.f / (1.f + __expf(-s));
}

// ================= persistent scan kernel: 256 blocks, 1 per CU =================
// Block p owns: hidden units j = 4p..4p+3 (all 4 gates, W_ih-ctx|W_hh in LDS, 98 KB)
//               att rows a = 4p..4p+3 (W_s in LDS, 16 KB)
// Per step: G (gates+cell) -> S (s_t, zero ctx slot) -> E (energies, exp, partial sums)
//           -> C (normalize, accum, context) with a device barrier between phases.
__global__ __launch_bounds__(256, 1) void k_scan(
    float* __restrict__ roA, float* __restrict__ cbuf,
    const float* __restrict__ gpre, const unsigned short* __restrict__ encctx,
    const float* __restrict__ ifert, float* __restrict__ accum,
    float* __restrict__ enw, float* __restrict__ st, float* __restrict__ pexp,
    const float* __restrict__ enc, const int* __restrict__ seqlen,
    const float* __restrict__ Wih, const float* __restrict__ Whh,
    const float* __restrict__ Wsm, const float* __restrict__ Wfb,
    const float* __restrict__ vatt, unsigned* bar) {
    __shared__ float Wg[16][1540];   // 16 gate-rows x (512 ctx | 1024 h), +4 pad vs bank conflicts
    __shared__ float Ws4[4][1028];   // 4 W_s rows
    __shared__ float redbuf[16];
    const int p = blockIdx.x, tid = threadIdx.x;
    const int lane = tid & 63, jj = tid >> 6;
    const int bg = lane >> 4, ks4 = (lane & 15) << 2;
    const bool ks0 = (lane & 15) == 0;
    const int j = 4 * p + jj;

    // ---- one-time preload of weight slices into LDS ----
    for (int r = 0; r < 16; r++) {
        int g = r & 3, j2 = 4 * p + (r >> 2);
        const float* s1 = Wih + (size_t)(g * HID + j2) * KX + EMB;
        const float* s2 = Whh + (size_t)(g * HID + j2) * HID;
        for (int k = tid * 4; k < 512; k += 1024) *(float4*)&Wg[r][k] = ld4(s1 + k);
        for (int k = tid * 4; k < 1024; k += 1024) *(float4*)&Wg[r][512 + k] = ld4(s2 + k);
    }
    for (int r = 0; r < 4; r++) {
        const float* s = Wsm + (size_t)(4 * p + r) * HID;
        for (int k = tid * 4; k < 1024; k += 1024) *(float4*)&Ws4[r][k] = ld4(s + k);
    }
    __syncthreads();

    unsigned barcnt = 0;
    for (int t = 0; t < Nsz; t++) {
        // ======== phase G: gates + LSTM cell ========
        float acc[4][4];
#pragma unroll
        for (int g = 0; g < 4; g++)
#pragma unroll
            for (int bb = 0; bb < 4; bb++) acc[g][bb] = 0.f;
        if (t > 0) {
            const float* xr[4];
#pragma unroll
            for (int bb = 0; bb < 4; bb++)
                xr[bb] = roA + ((size_t)((4 * bg + bb) * Nsz + (t - 1))) * KRO;
            const int r0 = jj * 4;
            for (int c = 0; c < 8; c++) {      // ctx part, k=0..511
                int k = c * 64 + ks4;
                float4 w0 = *(const float4*)&Wg[r0][k];
                float4 w1 = *(const float4*)&Wg[r0 + 1][k];
                float4 w2 = *(const float4*)&Wg[r0 + 2][k];
                float4 w3 = *(const float4*)&Wg[r0 + 3][k];
#pragma unroll
                for (int bb = 0; bb < 4; bb++) {
                    float4 x = ld4(xr[bb] + (HID + EMB) + k);
                    acc[0][bb] += dot4(w0, x); acc[1][bb] += dot4(w1, x);
                    acc[2][bb] += dot4(w2, x); acc[3][bb] += dot4(w3, x);
                }
            }
            for (int c = 0; c < 16; c++) {     // h part, k=512..1535
                int k = 512 + c * 64 + ks4;
                float4 w0 = *(const float4*)&Wg[r0][k];
                float4 w1 = *(const float4*)&Wg[r0 + 1][k];
                float4 w2 = *(const float4*)&Wg[r0 + 2][k];
                float4 w3 = *(const float4*)&Wg[r0 + 3][k];
#pragma unroll
                for (int bb = 0; bb < 4; bb++) {
                    float4 x = ld4(xr[bb] + (k - 512));
                    acc[0][bb] += dot4(w0, x); acc[1][bb] += dot4(w1, x);
                    acc[2][bb] += dot4(w2, x); acc[3][bb] += dot4(w3, x);
                }
            }
#pragma unroll
            for (int g = 0; g < 4; g++)
#pragma unroll
                for (int bb = 0; bb < 4; bb++) {
                    float v = acc[g][bb];
                    v += __shfl_xor(v, 1, 64); v += __shfl_xor(v, 2, 64);
                    v += __shfl_xor(v, 4, 64); v += __shfl_xor(v, 8, 64);
                    acc[g][bb] = v;
                }
        }
        if (ks0) {
#pragma unroll
            for (int bb = 0; bb < 4; bb++) {
                int b = 4 * bg + bb;
                const float* gp = gpre + ((size_t)(b * Nsz + t)) * G4 + j;
                float gi = acc[0][bb] + gp[0];
                float gf = acc[1][bb] + gp[HID];
                float gg = acc[2][bb] + gp[2 * HID];
                float go = acc[3][bb] + gp[3 * HID];
                float cold = (t > 0) ? cbuf[b * HID + j] : 0.f;
                float cn = sigmoidf_(gf) * cold + sigmoidf_(gi) * ftanh_(gg);
                float hn = sigmoidf_(go) * ftanh_(cn);
                cbuf[b * HID + j] = cn;
                roA[((size_t)(b * Nsz + t)) * KRO + j] = hn;
            }
        }
        barcnt++; gsync(bar, barcnt * 256u);

        // ======== phase S: s_t rows + zero ctx slot ========
        {
            float sa[4] = {0.f, 0.f, 0.f, 0.f};
            for (int c = 0; c < 16; c++) {
                int k = c * 64 + ks4;
                float4 w = *(const float4*)&Ws4[jj][k];
#pragma unroll
                for (int bb = 0; bb < 4; bb++) {
                    float4 x = ld4(roA + ((size_t)((4 * bg + bb) * Nsz + t)) * KRO + k);
                    sa[bb] += dot4(w, x);
                }
            }
#pragma unroll
            for (int bb = 0; bb < 4; bb++) {
                float v = sa[bb];
                v += __shfl_xor(v, 1, 64); v += __shfl_xor(v, 2, 64);
                v += __shfl_xor(v, 4, 64); v += __shfl_xor(v, 8, 64);
                if (ks0) st[(4 * bg + bb) * ATT + j] = v;
            }
            if (p < Bsz) {
                float* dst = roA + ((size_t)(p * Nsz + t)) * KRO + HID + EMB;
                dst[tid] = 0.f;
                dst[tid + 256] = 0.f;
            }
        }
        barcnt++; gsync(bar, barcnt * 256u);

        // ======== phase E: energies -> exp, per-block per-batch partial sums ========
        if (tid < 16) redbuf[tid] = 0.f;
        __syncthreads();
        for (int pair = p * 4 + jj; pair < Bsz * Tsz; pair += 1024) {
            int b = pair / Tsz, tt = pair - b * Tsz;
            float ew = 0.f;
            if (tt < seqlen[b]) {
                float ac = accum[pair];
                float e = 0.f;
#pragma unroll
                for (int it = 0; it < 2; it++) {
                    int k = lane * 8 + it * 512;
                    u16x8 c8 = *(const u16x8*)(encctx + (size_t)pair * ATT + k);
                    float4 s1 = ld4(st + b * ATT + k), s2 = ld4(st + b * ATT + k + 4);
                    float4 f1 = ld4(Wfb + k), f2 = ld4(Wfb + k + 4);
                    float4 v1 = ld4(vatt + k), v2 = ld4(vatt + k + 4);
                    e += ftanh_(bf2f(c8[0]) + s1.x + ac * f1.x) * v1.x;
                    e += ftanh_(bf2f(c8[1]) + s1.y + ac * f1.y) * v1.y;
                    e += ftanh_(bf2f(c8[2]) + s1.z + ac * f1.z) * v1.z;
                    e += ftanh_(bf2f(c8[3]) + s1.w + ac * f1.w) * v1.w;
                    e += ftanh_(bf2f(c8[4]) + s2.x + ac * f2.x) * v2.x;
                    e += ftanh_(bf2f(c8[5]) + s2.y + ac * f2.y) * v2.y;
                    e += ftanh_(bf2f(c8[6]) + s2.z + ac * f2.z) * v2.z;
                    e += ftanh_(bf2f(c8[7]) + s2.w + ac * f2.w) * v2.w;
                }
                for (int o = 32; o; o >>= 1) e += __shfl_xor(e, o, 64);
                ew = __expf(e);   // |e| <= sum|v_att| ~ 16, safe without max-shift
            }
            if (lane == 0) {
                enw[pair] = ew;
                if (ew > 0.f) atomicAdd(&redbuf[b], ew);
            }
        }
        __syncthreads();
        if (tid < 16) pexp[p * 16 + tid] = redbuf[tid];
        barcnt++; gsync(bar, barcnt * 256u);

        // ======== phase C: normalize, accum update, context reduction ========
        {
            int b = p >> 4, chunk = p & 15;
            float ps = pexp[tid * 16 + b];
            for (int o = 32; o; o >>= 1) ps += __shfl_xor(ps, o, 64);
            if (lane == 0) redbuf[jj] = ps;
            __syncthreads();
            float inv = 1.f / (redbuf[0] + redbuf[1] + redbuf[2] + redbuf[3]);
            int len = seqlen[b];
            int t0 = chunk * 63, t1 = min(t0 + 63, len);
            if (t0 < t1) {
                const float* row = enw + b * Tsz;
                for (int i = t0 + tid; i < t1; i += 256)
                    accum[b * Tsz + i] += row[i] * inv * ifert[b * Tsz + i] * 0.5f;
                float a0 = 0.f, a1 = 0.f;
                for (int i = t0; i < t1; i++) {
                    float w = row[i] * inv;
                    const float* er = enc + ((size_t)(b * Tsz + i)) * ENC;
                    a0 += w * er[tid];
                    a1 += w * er[tid + 256];
                }
                float* dst = roA + ((size_t)(b * Nsz + t)) * KRO + HID + EMB;
                atomicAdd(dst + tid, a0);
                atomicAdd(dst + tid + 256, a1);
            }
        }
        barcnt++; gsync(bar, barcnt * 256u);
    }
}

// ---------------- final small outputs ----------------
__global__ __launch_bounds__(256) void k_final(const float* __restrict__ roA, const float* __restrict__ cbuf,
                                               const float* __restrict__ accum, float* __restrict__ out) {
    int idx = blockIdx.x * 256 + threadIdx.x;
    const int base = Bsz * Nsz * VOCAB;
    const int OH = Bsz * HID, OC = Bsz * HID, OA = Bsz * ENC, OAC = Bsz * Tsz;
    if (idx < OH) {
        int b = idx / HID, j = idx % HID;
        out[base + idx] = roA[(size_t)(b * Nsz + Nsz - 1) * KRO + j];
        return;
    }
    idx -= OH;
    if (idx < OC) { out[base + OH + idx] = cbuf[idx]; return; }
    idx -= OC;
    if (idx < OA) {
        int b = idx / ENC, d = idx % ENC;
        out[base + OH + OC + idx] = roA[(size_t)(b * Nsz + Nsz - 1) * KRO + HID + EMB + d];
        return;
    }
    idx -= OA;
    if (idx < OAC) out[base + OH + OC + OA + idx] = accum[idx];
}

extern "C" void kernel_launch(void* const* d_in, const int* in_sizes, int n_in,
                              void* d_out, int out_size, void* d_ws, size_t ws_size,
                              hipStream_t stream) {
    const float* enc   = (const float*)d_in[0];
    const int* labels  = (const int*)d_in[1];
    const int* seqlen  = (const int*)d_in[2];
    const float* table = (const float*)d_in[3];
    const float* Wih   = (const float*)d_in[4];
    const float* Whh   = (const float*)d_in[5];
    const float* bih   = (const float*)d_in[6];
    const float* bhh   = (const float*)d_in[7];
    const float* Wsm   = (const float*)d_in[8];
    const float* Wenc  = (const float*)d_in[9];
    const float* benc  = (const float*)d_in[10];
    const float* vatt  = (const float*)d_in[11];
    const float* Wfert = (const float*)d_in[12];
    const float* Wfb   = (const float*)d_in[13];
    const float* Wro   = (const float*)d_in[14];
    const float* bro   = (const float*)d_in[15];
    const float* Wout  = (const float*)d_in[16];
    const float* bout  = (const float*)d_in[17];
    float* out = (float*)d_out;

    // workspace layout (floats); total ~19.14M floats = ~76.6 MB
    float* ws = (float*)d_ws;
    float* roA  = ws;                                 // [1600][KRO]
    float* cbuf = roA + (size_t)1600 * KRO;           // 16384
    float* gpre = cbuf + Bsz * HID;                   // [1600][4096]
    unsigned short* encctx = (unsigned short*)(gpre + (size_t)1600 * G4);  // [16000][1024] bf16
    float* ifert = gpre + (size_t)1600 * G4 + (size_t)Bsz * Tsz * ATT / 2;
    float* accum = ifert + Bsz * Tsz;                 // 16000
    float* enw   = accum + Bsz * Tsz;                 // 16000
    float* st    = enw + Bsz * Tsz;                   // 16384
    float* bsum  = st + Bsz * ATT;                    // 4096
    float* pexp  = bsum + G4;                         // 4096
    unsigned* bar = (unsigned*)(pexp + 4096);         // 16 slots
    float* rmx   = pexp + 4096 + 16;                  // [1600][512]

    k_init<<<(Bsz * Tsz + 255) / 256, 256, 0, stream>>>(accum, bih, bhh, bsum, bar);
    k_embed<<<(Bsz * Nsz * EMB + 255) / 256, 256, 0, stream>>>(labels, table, roA);
    // gpre = emb @ W_ih[:, :EMB]^T + (b_ih + b_hh)
    mfma_gemm<0><<<dim3(G4 / 128, (1600 + 127) / 128), 256, 0, stream>>>(
        roA + HID, KRO, Wih, KX, bsum, gpre, 1600, G4, EMB, G4);
    // enc_ctx = enc @ W_enc^T + b_enc -> bf16
    mfma_gemm<2><<<dim3(ATT / 128, (Bsz * Tsz) / 128), 256, 0, stream>>>(
        enc, ENC, Wenc, ENC, benc, (float*)encctx, Bsz * Tsz, ATT, ENC, ATT);
    k_ifert<<<(Bsz * Tsz * 64 + 255) / 256, 256, 0, stream>>>(enc, Wfert, ifert);

    // entire 100-step scan in one persistent kernel (256 blocks = 1/CU)
    k_scan<<<256, 256, 0, stream>>>(roA, cbuf, gpre, encctx, ifert, accum, enw, st, pexp,
                                    enc, seqlen, Wih, Whh, Wsm, Wfb, vatt, bar);

    // readout: [1600,2176]@[2176,1024] + bias -> maxout -> rmx [1600,512]
    mfma_gemm<1><<<dim3(1024 / 128, (1600 + 127) / 128), 256, 0, stream>>>(
        roA, KRO, Wro, KRO, bro, rmx, 1600, 1024, KRO, 512);
    // logits: [1600,512]@[512,10025] + bias -> d_out
    mfma_gemm<0><<<dim3((VOCAB + 127) / 128, (1600 + 127) / 128), 256, 0, stream>>>(
        rmx, 512, Wout, 512, bout, out, 1600, VOCAB, 512, VOCAB);
    k_final<<<(Bsz * HID * 2 + Bsz * ENC + Bsz * Tsz + 255) / 256, 256, 0, stream>>>(roA, cbuf, accum, out);
}